// Round 3
// baseline (142.134 us; speedup 1.0000x reference)
//
#include <hip/hip_runtime.h>
#include <math.h>

// ---------------------------------------------------------------------------
// NFFT forward (type-2): f_hat (B,C,256,256 complex) -> samples at M points.
// R12: 2 dispatches. rows+cols FUSED into one kernel (512 co-resident blocks,
// monotonic device-scope spin barrier between phases) — removes one ~10-12us
// dispatch boundary. FFT cores + gather are the proven R10 forms (radix-2,
// stage-0 fused into staging; 8-lane gather) — R11's radix-4 + 4-lane gather
// regressed (gather is latency-bound; halving waves halved latency hiding).
//   phase A (rows): channel-merged fused deconvolve/pad/fftshift + 512-pt
//         row FFT. Both channels ride in a float4 (re0,im0,re1,im1).
//         Stage-0 fused into staging (pair partner always zero).
//   phase B (cols): 2-column tiles (512 tiles = 512 blocks, 2 blocks/CU vs
//         R10's 1), stage-0 fused into load (zero middle rows never touch
//         LDS), unrolled stages with hoisted twiddles. Output packed bf16x4
//         into the never-written middle-row region of G32 (2 MB/image).
//   gather: 8 lanes per (b,point); per row-tap ONE 8B load/lane yields both
//         channels. rsq/__expf/v_rcp weight path.
// Barrier: monotonic counter (no reset needed across graph replays):
//   old = atomicAdd(cnt); target = (old/512+1)*512; spin until cnt>=target.
//   All 512 blocks are co-resident (16.4 KB LDS, <=256 VGPR -> >=2 blocks/CU)
//   so the spin cannot deadlock. __threadfence (agent) on both sides for
//   cross-XCD visibility (G12/G16).
// Shift algebra: ifftshift(FFT(fftshift(p)))[(ind+256)%512] == FFT(fftshift(p))[ind&511].
// Output PLANAR: real plane (B,C,M) then imag plane.
// R4: no forced __launch_bounds__ minima (spill -> dead kernel).
// R7: ~12-15us per dispatch boundary. R8: cooperative grid.sync catastrophic.
// ---------------------------------------------------------------------------

#define NGRID 512
#define NSMALL 256
#define MW 4
#define BB 2
#define CC 2
#define MPTS 200000
#define PLANE (BB * CC * MPTS)   // imag-plane offset in floats
#define LPAD4 513                // LDS pitch in float4 (breaks pow2 banking)
#define IMG4 (NGRID * NGRID)     // float4 elems per b-image in G32
#define NBLK 512                 // fused-kernel grid (must all be co-resident)
// G16 (uint2 units): image b's packed grid lives in G32's middle rows
#define G16OFF(b) ((size_t)(b) * 524288 + 131072)

__device__ unsigned nfft29781_bar = 0;   // monotonic grid-barrier counter

// I0(z) asymptotic series, valid z > 8 (our z in [17.7, 18.9])
__device__ __forceinline__ float nfft29781_i0_large(float z) {
    float inv = __builtin_amdgcn_rcpf(z);
    float p = 1.0f + inv * (0.125f + inv * (0.0703125f
              + inv * (0.0732421875f + inv * 0.112152099609375f)));
    return __expf(z) * rsqrtf(2.0f * (float)M_PI * z) * p;
}

__device__ __forceinline__ int nfft29781_brev9(int v) {
    return (int)(__brev((unsigned)v) >> 23);
}

__device__ __forceinline__ unsigned nfft29781_bf16pack(float a, float b) {
    unsigned ua = __float_as_uint(a);
    ua += 0x7FFFu + ((ua >> 16) & 1u);           // RNE
    unsigned ub = __float_as_uint(b);
    ub += 0x7FFFu + ((ub >> 16) & 1u);
    return (ua >> 16) | (ub & 0xFFFF0000u);
}

// ---------------------------------------------------------------------------
// Fused rows+cols 2D FFT. Grid: exactly NBLK=512 blocks of 256 threads.
// ---------------------------------------------------------------------------
__global__ __launch_bounds__(256) void nfft29781_fft2d(const float* __restrict__ fr,
                                                       const float* __restrict__ fi,
                                                       float4* __restrict__ G32) {
    __shared__ float4 s[2 * LPAD4];                 // 16.4 KB (cols needs 2 cols)
    int tid = threadIdx.x;

    // ---------------- phase A: rows ----------------
    {
        int b   = blockIdx.x >> 8;
        int a1  = blockIdx.x & 255;

        const float bcon  = 1.5f * (float)M_PI;
        const float scale = 2.0f * (float)M_PI / (float)NGRID;
        float k1 = (float)(a1 - 128) * scale;
        float p1 = nfft29781_i0_large((float)MW * sqrtf(bcon * bcon - k1 * k1));

        int a2 = tid ^ 128;
        float k2 = (float)(a2 - 128) * scale;
        float p2 = nfft29781_i0_large((float)MW * sqrtf(bcon * bcon - k2 * k2));
        float invp = __builtin_amdgcn_rcpf(p1 * p2);

        size_t s0 = ((size_t)(b * CC + 0) * NSMALL + a1) * NSMALL + a2;
        size_t s1 = ((size_t)(b * CC + 1) * NSMALL + a1) * NSMALL + a2;
        float4 v = make_float4(fr[s0] * invp, fi[s0] * invp,
                               fr[s1] * invp, fi[s1] * invp);

        // fused stage 0: nonzero staged col pairs with an all-zero partner.
        int j2v = (tid < 128) ? tid : tid + 256;
        int pidx = nfft29781_brev9(j2v);
        int pe = pidx & ~1;
        s[pe]     = v;
        s[pe + 1] = (pidx & 1) ? make_float4(-v.x, -v.y, -v.z, -v.w) : v;
        __syncthreads();

        // stages 1..8 radix-2 (proven R10 core)
        #pragma unroll
        for (int st = 1; st < 9; ++st) {
            int half = 1 << st;
            int pos = tid & (half - 1);
            int i0 = ((tid >> st) << (st + 1)) + pos;
            int i1 = i0 + half;
            float sn, cs;
            if (st == 1) {                          // twiddle 1 or -i
                cs = pos ? 0.0f : 1.0f;
                sn = pos ? -1.0f : 0.0f;
            } else {
                float ang = -(float)M_PI * (float)pos / (float)half;
                __sincosf(ang, &sn, &cs);
            }
            float4 a = s[i0];
            float4 bq = s[i1];
            float4 tw;
            tw.x = bq.x * cs - bq.y * sn;  tw.y = bq.x * sn + bq.y * cs;
            tw.z = bq.z * cs - bq.w * sn;  tw.w = bq.z * sn + bq.w * cs;
            s[i0] = make_float4(a.x + tw.x, a.y + tw.y, a.z + tw.z, a.w + tw.w);
            s[i1] = make_float4(a.x - tw.x, a.y - tw.y, a.z - tw.z, a.w - tw.w);
            __syncthreads();
        }

        int j1 = (a1 < 128) ? a1 + 384 : a1 - 128;  // staged row (fftshift fold)
        float4* Gb = G32 + (size_t)b * IMG4 + (size_t)j1 * NGRID;
        Gb[tid]       = s[tid];
        Gb[tid + 256] = s[tid + 256];
    }

    // ---------------- grid barrier (monotonic, self-resetting) -------------
    __syncthreads();                                // all stores issued+drained
    if (tid == 0) {
        __threadfence();                            // agent-scope release
        unsigned old = __hip_atomic_fetch_add(&nfft29781_bar, 1u,
                           __ATOMIC_ACQ_REL, __HIP_MEMORY_SCOPE_AGENT);
        unsigned target = (old / (unsigned)NBLK + 1u) * (unsigned)NBLK;
        while (__hip_atomic_load(&nfft29781_bar, __ATOMIC_RELAXED,
                                 __HIP_MEMORY_SCOPE_AGENT) < target) {
            __builtin_amdgcn_s_sleep(1);
        }
        __threadfence();                            // agent-scope acquire
    }
    __syncthreads();

    // ---------------- phase B: cols (2-column tiles) ----------------
    {
        int b    = blockIdx.x >> 8;
        int col0 = (blockIdx.x & 255) << 1;
        const float4* Gb = G32 + (size_t)b * IMG4;

        // load 256 nonzero rows x 2 cols; fused stage 0: each bit-reversed
        // stage-0 pair (r, r+256) has exactly one nonzero member.
        #pragma unroll
        for (int it = 0; it < 2; ++it) {
            int e  = it * 256 + tid;                // 0..511
            int cp = e & 1;
            int q  = e >> 1;                        // 0..255
            int r  = (q < 128) ? q : q + 256;       // nonzero row
            float4 v = Gb[(size_t)r * NGRID + col0 + cp];
            int pidx = nfft29781_brev9(r);
            int pe = pidx & ~1;
            float4* scw = s + cp * LPAD4;
            scw[pe]     = v;
            scw[pe + 1] = (pidx & 1) ? make_float4(-v.x, -v.y, -v.z, -v.w) : v;
        }
        __syncthreads();

        // 2 column-FFTs in parallel: c owns a column, w does 2 butterflies
        // per stage (bf = w, w+128). For half<=128 both share pos -> 1 sincos.
        int c = tid & 1;
        int w = tid >> 1;                           // 0..127
        float4* sc = s + c * LPAD4;
        #pragma unroll
        for (int st = 1; st < 9; ++st) {
            const int half = 1 << st;
            float csk[2], snk[2];
            if (st == 1) {
                int pos = w & 1;
                csk[0] = pos ? 0.0f : 1.0f;
                snk[0] = pos ? -1.0f : 0.0f;
                csk[1] = csk[0]; snk[1] = snk[0];
            } else if (st < 8) {
                int pos = w & (half - 1);
                float ang = -(float)M_PI * (float)pos / (float)half;
                __sincosf(ang, &snk[0], &csk[0]);
                csk[1] = csk[0]; snk[1] = snk[0];
            } else {
                float ang0 = -(float)M_PI * (float)w / 256.0f;
                __sincosf(ang0, &snk[0], &csk[0]);
                float ang1 = -(float)M_PI * (float)(w + 128) / 256.0f;
                __sincosf(ang1, &snk[1], &csk[1]);
            }
            #pragma unroll
            for (int k = 0; k < 2; ++k) {
                int bf  = w + (k << 7);             // 0..255
                int pos = bf & (half - 1);
                int i0  = ((bf >> st) << (st + 1)) + pos;
                int i1  = i0 + half;
                float cs = csk[k], sn = snk[k];
                float4 a = sc[i0];
                float4 bb = sc[i1];
                float4 tw;
                tw.x = bb.x * cs - bb.y * sn;  tw.y = bb.x * sn + bb.y * cs;
                tw.z = bb.z * cs - bb.w * sn;  tw.w = bb.z * sn + bb.w * cs;
                sc[i0] = make_float4(a.x + tw.x, a.y + tw.y, a.z + tw.z, a.w + tw.w);
                sc[i1] = make_float4(a.x - tw.x, a.y - tw.y, a.z - tw.z, a.w - tw.w);
            }
            __syncthreads();
        }

        // pack + write all 512 rows x 2 cols into the middle-row region
        uint2* G16 = (uint2*)G32 + G16OFF(b);
        #pragma unroll
        for (int it = 0; it < 4; ++it) {
            int e  = it * 256 + tid;                // 0..1023
            int cp = e & 1;
            int r  = e >> 1;                        // 0..511
            float4 v = s[cp * LPAD4 + r];
            uint2 pk;
            pk.x = nfft29781_bf16pack(v.x, v.y);    // ch0 re|im
            pk.y = nfft29781_bf16pack(v.z, v.w);    // ch1 re|im
            G16[(size_t)r * NGRID + col0 + cp] = pk;
        }
    }
}

// ---------------------------------------------------------------------------
// Gather (proven R10 form): 8 lanes per (b,point); lane j owns column-tap j.
// Per row-tap ONE 8B load/lane -> both channels (bf16x4). Weights computed
// once per group, w0[i] broadcast via __shfl; 3-stage __shfl_xor sums; lane 0
// writes planar. Weight sequence bit-matches reference ceil(x*n)-m.
// ---------------------------------------------------------------------------
__global__ __launch_bounds__(256) void nfft29781_gather_bf16(const float* __restrict__ x,
                                                             const uint2* __restrict__ G16base,
                                                             float* __restrict__ out,
                                                             int out_elems) {
    int t  = blockIdx.x * blockDim.x + threadIdx.x;
    int j  = t & 7;                  // my column tap
    int pp = t >> 3;                 // (b, point) id — shared by 8 group lanes
    if (pp >= BB * MPTS) return;
    int b  = (pp >= MPTS) ? 1 : 0;
    int pt = pp - b * MPTS;

    float u0 = x[(size_t)pp * 2 + 0] * (float)NGRID;   // broadcast within group
    float u1 = x[(size_t)pp * 2 + 1] * (float)NGRID;

    float c0 = ceilf(u0), c1 = ceilf(u1);
    int base0 = (int)c0 - MW;
    int base1 = (int)c1 - MW;
    float d0 = c0 - u0, d1 = c1 - u1;

    const float bw = 1.5f * (float)M_PI;
    const float invpi = 1.0f / (float)M_PI;
    float w0m, w1m;   // my dim-0 / dim-1 tap-j weights
    {
        float nk = (float)(MW - j) - d0;
        float tt = (float)(MW * MW) - nk * nk;
        w0m = 0.0f;
        if (tt > 0.0f) {
            float ra = __builtin_amdgcn_rsqf(tt);    // 1/a
            float a  = tt * ra;                      // a = sqrt(tt)
            float e  = __expf(bw * a);
            w0m = (e - __builtin_amdgcn_rcpf(e)) * (0.5f * invpi) * ra;
        }
        nk = (float)(MW - j) - d1;
        tt = (float)(MW * MW) - nk * nk;
        w1m = 0.0f;
        if (tt > 0.0f) {
            float ra = __builtin_amdgcn_rsqf(tt);
            float a  = tt * ra;
            float e  = __expf(bw * a);
            w1m = (e - __builtin_amdgcn_rcpf(e)) * (0.5f * invpi) * ra;
        }
    }

    const uint2* Gi = G16base + G16OFF(b);
    int cix = (base1 + j) & (NGRID - 1);
    int lanebase = (threadIdx.x & 63) & ~7;

    float a0x = 0.0f, a0y = 0.0f, a1x = 0.0f, a1y = 0.0f;
    #pragma unroll
    for (int i = 0; i < 8; ++i) {
        float w0i = __shfl(w0m, lanebase + i, 64);   // row-i weight
        uint2 g = Gi[(size_t)(((base0 + i) & (NGRID - 1)) << 9) + cix];
        float g0x = __uint_as_float(g.x << 16);
        float g0y = __uint_as_float(g.x & 0xFFFF0000u);
        float g1x = __uint_as_float(g.y << 16);
        float g1y = __uint_as_float(g.y & 0xFFFF0000u);
        a0x += w0i * g0x;  a0y += w0i * g0y;
        a1x += w0i * g1x;  a1y += w0i * g1y;
    }
    a0x *= w1m;  a0y *= w1m;  a1x *= w1m;  a1y *= w1m;

    #pragma unroll
    for (int msk = 1; msk < 8; msk <<= 1) {          // sum the 8 column taps
        a0x += __shfl_xor(a0x, msk, 64);
        a0y += __shfl_xor(a0y, msk, 64);
        a1x += __shfl_xor(a1x, msk, 64);
        a1y += __shfl_xor(a1y, msk, 64);
    }

    if (j == 0) {
        size_t o0 = (size_t)(b * CC) * MPTS + pt;    // channel 0
        size_t o1 = o0 + MPTS;                       // channel 1
        if (o0 < (size_t)out_elems)         out[o0]         = a0x;
        if (PLANE + o0 < (size_t)out_elems) out[PLANE + o0] = a0y;
        if (o1 < (size_t)out_elems)         out[o1]         = a1x;
        if (PLANE + o1 < (size_t)out_elems) out[PLANE + o1] = a1y;
    }
}

extern "C" void kernel_launch(void* const* d_in, const int* in_sizes, int n_in,
                              void* d_out, int out_size, void* d_ws, size_t ws_size,
                              hipStream_t stream) {
    (void)in_sizes; (void)n_in;
    const float* x  = (const float*)d_in[0];
    const float* fr = (const float*)d_in[1];
    const float* fi = (const float*)d_in[2];
    float*  out = (float*)d_out;
    float4* G32 = (float4*)d_ws;        // BB * 512*512 float4 = 8 MB

    const size_t fullBytes = (size_t)BB * IMG4 * sizeof(float4);
    if (ws_size < fullBytes) return;    // diagnostic no-op (ws proven >= 8 MB)

    nfft29781_fft2d<<<NBLK, 256, 0, stream>>>(fr, fi, G32);
    int gthreads = BB * MPTS * 8;       // 8 lanes per (b,point), both channels
    nfft29781_gather_bf16<<<(gthreads + 255) / 256, 256, 0, stream>>>(
        x, (const uint2*)d_ws, out, out_size);
}

// Round 5
// 96.306 us; speedup vs baseline: 1.4759x; 1.4759x over previous
//
#include <hip/hip_runtime.h>
#include <math.h>

// ---------------------------------------------------------------------------
// NFFT forward (type-2): f_hat (B,C,256,256 complex) -> samples at M points.
// R14 == R13 resubmitted (R13 bench died to container-acquisition infra
// failure, not the kernel; source re-reviewed for safety — no OOB, no spins).
// R13: back to 3 dispatches (R12 proved ANY cross-XCD spin rendezvous costs
// ~45us on 8 XCDs — worse than the ~3-5us dispatch boundary it replaces).
//   rows: TWO rows per block (256 blocks, 16KB LDS). Thread t runs
//         butterfly t in both rows -> one sincos serves two butterflies,
//         2 independent chains/thread (ILP), half the device-wide barriers.
//         Stage-0 fused into staging (pair partner always zero, R10).
//   cols: 2-column tiles x 512 blocks (2 blocks/CU). Thread t = butterfly
//         index applied to BOTH columns -> 1 sincos/stage (7 total), stage-0
//         fused into load (zero middle rows never touch LDS). Output packed
//         bf16x4 into the never-written middle-row region of G32.
//   gather: proven R10 form untouched (latency-bound; R11 showed halving
//         waves hurts). 8 lanes per (b,point); ONE 8B load/lane per row-tap
//         yields both channels; rsq/__expf/v_rcp weight path.
// Shift algebra: ifftshift(FFT(fftshift(p)))[(ind+256)%512] == FFT(fftshift(p))[ind&511].
// Output PLANAR: real plane (B,C,M) then imag plane.
// R4: no forced __launch_bounds__ minima (spill -> dead kernel).
// R7: boundaries ~3-5us (R12 deduction). R8/R12: grid sync catastrophic.
// ---------------------------------------------------------------------------

#define NGRID 512
#define NSMALL 256
#define MW 4
#define BB 2
#define CC 2
#define MPTS 200000
#define PLANE (BB * CC * MPTS)   // imag-plane offset in floats
#define LPAD4 513                // LDS pitch in float4 (breaks pow2 banking)
#define IMG4 (NGRID * NGRID)     // float4 elems per b-image in G32
// G16 (uint2 units): image b's packed grid lives in G32's middle rows
#define G16OFF(b) ((size_t)(b) * 524288 + 131072)

// I0(z) asymptotic series, valid z > 8 (our z in [17.7, 18.9])
__device__ __forceinline__ float nfft29781_i0_large(float z) {
    float inv = __builtin_amdgcn_rcpf(z);
    float p = 1.0f + inv * (0.125f + inv * (0.0703125f
              + inv * (0.0732421875f + inv * 0.112152099609375f)));
    return __expf(z) * rsqrtf(2.0f * (float)M_PI * z) * p;
}

__device__ __forceinline__ int nfft29781_brev9(int v) {
    return (int)(__brev((unsigned)v) >> 23);
}

__device__ __forceinline__ unsigned nfft29781_bf16pack(float a, float b) {
    unsigned ua = __float_as_uint(a);
    ua += 0x7FFFu + ((ua >> 16) & 1u);           // RNE
    unsigned ub = __float_as_uint(b);
    ub += 0x7FFFu + ((ub >> 16) & 1u);
    return (ua >> 16) | (ub & 0xFFFF0000u);
}

// radix-2 butterfly on channel-packed float4 complex pair, twiddle (cs,sn)
__device__ __forceinline__ void nfft29781_bfly(float4* s, int i0, int i1,
                                               float cs, float sn) {
    float4 a = s[i0];
    float4 b = s[i1];
    float4 tw;
    tw.x = b.x * cs - b.y * sn;  tw.y = b.x * sn + b.y * cs;
    tw.z = b.z * cs - b.w * sn;  tw.w = b.z * sn + b.w * cs;
    s[i0] = make_float4(a.x + tw.x, a.y + tw.y, a.z + tw.z, a.w + tw.w);
    s[i1] = make_float4(a.x - tw.x, a.y - tw.y, a.z - tw.z, a.w - tw.w);
}

// ---------------------------------------------------------------------------
// Rows: one block per (b, row-pair); 256 blocks x 256 threads, 2 rows/block.
// Thread t does butterfly t in BOTH rows with one shared twiddle.
// ---------------------------------------------------------------------------
__global__ __launch_bounds__(256) void nfft29781_rows2(const float* __restrict__ fr,
                                                       const float* __restrict__ fi,
                                                       float4* __restrict__ G32) {
    __shared__ float4 sA[NGRID];
    __shared__ float4 sB[NGRID];
    int tid = threadIdx.x;
    int b   = blockIdx.x >> 7;
    int pr  = blockIdx.x & 127;
    int a1A = pr * 2;
    int a1B = pr * 2 + 1;

    const float bcon  = 1.5f * (float)M_PI;
    const float scale = 2.0f * (float)M_PI / (float)NGRID;
    float k1A = (float)(a1A - 128) * scale;
    float p1A = nfft29781_i0_large((float)MW * sqrtf(bcon * bcon - k1A * k1A));
    float k1B = (float)(a1B - 128) * scale;
    float p1B = nfft29781_i0_large((float)MW * sqrtf(bcon * bcon - k1B * k1B));

    int a2 = tid ^ 128;
    float k2 = (float)(a2 - 128) * scale;
    float p2 = nfft29781_i0_large((float)MW * sqrtf(bcon * bcon - k2 * k2));
    float invpA = __builtin_amdgcn_rcpf(p1A * p2);
    float invpB = __builtin_amdgcn_rcpf(p1B * p2);

    size_t s0A = ((size_t)(b * CC + 0) * NSMALL + a1A) * NSMALL + a2;
    size_t s1A = ((size_t)(b * CC + 1) * NSMALL + a1A) * NSMALL + a2;
    size_t s0B = ((size_t)(b * CC + 0) * NSMALL + a1B) * NSMALL + a2;
    size_t s1B = ((size_t)(b * CC + 1) * NSMALL + a1B) * NSMALL + a2;
    float4 vA = make_float4(fr[s0A] * invpA, fi[s0A] * invpA,
                            fr[s1A] * invpA, fi[s1A] * invpA);
    float4 vB = make_float4(fr[s0B] * invpB, fi[s0B] * invpB,
                            fr[s1B] * invpB, fi[s1B] * invpB);

    // fused stage 0: nonzero staged col pairs with an all-zero partner.
    int j2v = (tid < 128) ? tid : tid + 256;
    int pidx = nfft29781_brev9(j2v);
    int pe = pidx & ~1;
    int odd = pidx & 1;
    sA[pe]     = vA;
    sA[pe + 1] = odd ? make_float4(-vA.x, -vA.y, -vA.z, -vA.w) : vA;
    sB[pe]     = vB;
    sB[pe + 1] = odd ? make_float4(-vB.x, -vB.y, -vB.z, -vB.w) : vB;
    __syncthreads();

    // stages 1..8 radix-2; one twiddle drives both rows' butterflies
    #pragma unroll
    for (int st = 1; st < 9; ++st) {
        int half = 1 << st;
        int pos = tid & (half - 1);
        int i0 = ((tid >> st) << (st + 1)) + pos;
        int i1 = i0 + half;
        float sn, cs;
        if (st == 1) {                          // twiddle 1 or -i
            cs = pos ? 0.0f : 1.0f;
            sn = pos ? -1.0f : 0.0f;
        } else {
            float ang = -(float)M_PI * (float)pos / (float)half;
            __sincosf(ang, &sn, &cs);
        }
        nfft29781_bfly(sA, i0, i1, cs, sn);
        nfft29781_bfly(sB, i0, i1, cs, sn);
        __syncthreads();
    }

    int j1A = (a1A < 128) ? a1A + 384 : a1A - 128;  // staged row (fftshift fold)
    int j1B = (a1B < 128) ? a1B + 384 : a1B - 128;
    float4* GbA = G32 + (size_t)b * IMG4 + (size_t)j1A * NGRID;
    float4* GbB = G32 + (size_t)b * IMG4 + (size_t)j1B * NGRID;
    GbA[tid]       = sA[tid];
    GbA[tid + 256] = sA[tid + 256];
    GbB[tid]       = sB[tid];
    GbB[tid + 256] = sB[tid + 256];
}

// ---------------------------------------------------------------------------
// Cols: one block per (b, 2-col group); 512 blocks (2/CU). Reads the 256
// nonzero rows (fp32 float4); stage 0 fused into staging; thread t = butterfly
// index applied to both columns (1 sincos/stage); packs result to bf16x4 into
// G32's middle-row region (disjoint from reads).
// ---------------------------------------------------------------------------
__global__ __launch_bounds__(256) void nfft29781_cols2(float4* __restrict__ G32) {
    __shared__ float4 s[2 * LPAD4];                 // 16.4 KB
    int tid  = threadIdx.x;
    int b    = blockIdx.x >> 8;
    int col0 = (blockIdx.x & 255) << 1;
    const float4* Gb = G32 + (size_t)b * IMG4;

    // load 256 nonzero rows x 2 cols; fused stage 0: each bit-reversed
    // stage-0 pair (r, r+256) has exactly one nonzero member.
    #pragma unroll
    for (int it = 0; it < 2; ++it) {
        int e  = it * 256 + tid;                    // 0..511
        int cp = e & 1;
        int q  = e >> 1;                            // 0..255
        int r  = (q < 128) ? q : q + 256;           // nonzero row
        float4 v = Gb[(size_t)r * NGRID + col0 + cp];
        int pidx = nfft29781_brev9(r);
        int pe = pidx & ~1;
        float4* scw = s + cp * LPAD4;
        scw[pe]     = v;
        scw[pe + 1] = (pidx & 1) ? make_float4(-v.x, -v.y, -v.z, -v.w) : v;
    }
    __syncthreads();

    // stages 1..8: thread t owns butterfly t in BOTH columns (shared twiddle)
    float4* sc0 = s;
    float4* sc1 = s + LPAD4;
    #pragma unroll
    for (int st = 1; st < 9; ++st) {
        int half = 1 << st;
        int pos = tid & (half - 1);
        int i0 = ((tid >> st) << (st + 1)) + pos;
        int i1 = i0 + half;
        float sn, cs;
        if (st == 1) {                          // twiddle 1 or -i
            cs = pos ? 0.0f : 1.0f;
            sn = pos ? -1.0f : 0.0f;
        } else {
            float ang = -(float)M_PI * (float)pos / (float)half;
            __sincosf(ang, &sn, &cs);
        }
        nfft29781_bfly(sc0, i0, i1, cs, sn);
        nfft29781_bfly(sc1, i0, i1, cs, sn);
        __syncthreads();
    }

    // pack + write all 512 rows x 2 cols into the middle-row region (uint2)
    uint2* G16 = (uint2*)G32 + G16OFF(b);
    #pragma unroll
    for (int it = 0; it < 4; ++it) {
        int e  = it * 256 + tid;                    // 0..1023
        int cp = e & 1;
        int r  = e >> 1;                            // 0..511
        float4 v = s[cp * LPAD4 + r];
        uint2 pk;
        pk.x = nfft29781_bf16pack(v.x, v.y);        // ch0 re|im
        pk.y = nfft29781_bf16pack(v.z, v.w);        // ch1 re|im
        G16[(size_t)r * NGRID + col0 + cp] = pk;
    }
}

// ---------------------------------------------------------------------------
// Gather (proven R10 form, untouched): 8 lanes per (b,point); lane j owns
// column-tap j. Per row-tap ONE 8B load/lane -> both channels (bf16x4).
// Weights computed once per group, w0[i] broadcast via __shfl; 3-stage
// __shfl_xor sums; lane 0 writes planar. Bit-matches reference ceil(x*n)-m.
// ---------------------------------------------------------------------------
__global__ __launch_bounds__(256) void nfft29781_gather_bf16(const float* __restrict__ x,
                                                             const uint2* __restrict__ G16base,
                                                             float* __restrict__ out,
                                                             int out_elems) {
    int t  = blockIdx.x * blockDim.x + threadIdx.x;
    int j  = t & 7;                  // my column tap
    int pp = t >> 3;                 // (b, point) id — shared by 8 group lanes
    if (pp >= BB * MPTS) return;
    int b  = (pp >= MPTS) ? 1 : 0;
    int pt = pp - b * MPTS;

    float u0 = x[(size_t)pp * 2 + 0] * (float)NGRID;   // broadcast within group
    float u1 = x[(size_t)pp * 2 + 1] * (float)NGRID;

    float c0 = ceilf(u0), c1 = ceilf(u1);
    int base0 = (int)c0 - MW;
    int base1 = (int)c1 - MW;
    float d0 = c0 - u0, d1 = c1 - u1;

    const float bw = 1.5f * (float)M_PI;
    const float invpi = 1.0f / (float)M_PI;
    float w0m, w1m;   // my dim-0 / dim-1 tap-j weights
    {
        float nk = (float)(MW - j) - d0;
        float tt = (float)(MW * MW) - nk * nk;
        w0m = 0.0f;
        if (tt > 0.0f) {
            float ra = __builtin_amdgcn_rsqf(tt);    // 1/a
            float a  = tt * ra;                      // a = sqrt(tt)
            float e  = __expf(bw * a);
            w0m = (e - __builtin_amdgcn_rcpf(e)) * (0.5f * invpi) * ra;
        }
        nk = (float)(MW - j) - d1;
        tt = (float)(MW * MW) - nk * nk;
        w1m = 0.0f;
        if (tt > 0.0f) {
            float ra = __builtin_amdgcn_rsqf(tt);
            float a  = tt * ra;
            float e  = __expf(bw * a);
            w1m = (e - __builtin_amdgcn_rcpf(e)) * (0.5f * invpi) * ra;
        }
    }

    const uint2* Gi = G16base + G16OFF(b);
    int cix = (base1 + j) & (NGRID - 1);
    int lanebase = (threadIdx.x & 63) & ~7;

    float a0x = 0.0f, a0y = 0.0f, a1x = 0.0f, a1y = 0.0f;
    #pragma unroll
    for (int i = 0; i < 8; ++i) {
        float w0i = __shfl(w0m, lanebase + i, 64);   // row-i weight
        uint2 g = Gi[(size_t)(((base0 + i) & (NGRID - 1)) << 9) + cix];
        float g0x = __uint_as_float(g.x << 16);
        float g0y = __uint_as_float(g.x & 0xFFFF0000u);
        float g1x = __uint_as_float(g.y << 16);
        float g1y = __uint_as_float(g.y & 0xFFFF0000u);
        a0x += w0i * g0x;  a0y += w0i * g0y;
        a1x += w0i * g1x;  a1y += w0i * g1y;
    }
    a0x *= w1m;  a0y *= w1m;  a1x *= w1m;  a1y *= w1m;

    #pragma unroll
    for (int msk = 1; msk < 8; msk <<= 1) {          // sum the 8 column taps
        a0x += __shfl_xor(a0x, msk, 64);
        a0y += __shfl_xor(a0y, msk, 64);
        a1x += __shfl_xor(a1x, msk, 64);
        a1y += __shfl_xor(a1y, msk, 64);
    }

    if (j == 0) {
        size_t o0 = (size_t)(b * CC) * MPTS + pt;    // channel 0
        size_t o1 = o0 + MPTS;                       // channel 1
        if (o0 < (size_t)out_elems)         out[o0]         = a0x;
        if (PLANE + o0 < (size_t)out_elems) out[PLANE + o0] = a0y;
        if (o1 < (size_t)out_elems)         out[o1]         = a1x;
        if (PLANE + o1 < (size_t)out_elems) out[PLANE + o1] = a1y;
    }
}

extern "C" void kernel_launch(void* const* d_in, const int* in_sizes, int n_in,
                              void* d_out, int out_size, void* d_ws, size_t ws_size,
                              hipStream_t stream) {
    (void)in_sizes; (void)n_in;
    const float* x  = (const float*)d_in[0];
    const float* fr = (const float*)d_in[1];
    const float* fi = (const float*)d_in[2];
    float*  out = (float*)d_out;
    float4* G32 = (float4*)d_ws;        // BB * 512*512 float4 = 8 MB

    const size_t fullBytes = (size_t)BB * IMG4 * sizeof(float4);
    if (ws_size < fullBytes) return;    // diagnostic no-op (ws proven >= 8 MB)

    nfft29781_rows2<<<BB * 128, 256, 0, stream>>>(fr, fi, G32);
    nfft29781_cols2<<<BB * (NGRID / 2), 256, 0, stream>>>(G32);
    int gthreads = BB * MPTS * 8;       // 8 lanes per (b,point), both channels
    nfft29781_gather_bf16<<<(gthreads + 255) / 256, 256, 0, stream>>>(
        x, (const uint2*)d_ws, out, out_size);
}

// Round 6
// 95.870 us; speedup vs baseline: 1.4826x; 1.0045x over previous
//
#include <hip/hip_runtime.h>
#include <math.h>

// ---------------------------------------------------------------------------
// NFFT forward (type-2): f_hat (B,C,256,256 complex) -> samples at M points.
// R15: rows/cols restored to the R10-proven forms byte-for-byte (94.95us
// config; R11 radix-4 and R14 2-row/2-col variants both regressed). Gather
// keeps R10's proven memory pattern + wave count but re-schedules:
//   - all 8 scattered uint2 loads issued upfront into registers (one vmcnt
//     batch, no lgkm(bpermute) interleaved between loads),
//   - all 8 __shfl weight broadcasts batched after,
//   - float2 accumulation to invite v_pk_fma_f32 packing.
// History: R8/R12 grid-sync catastrophic (~45us). Boundaries ~3-5us.
// R11: 4-lane gather regressed (latency-bound; fewer waves = less hiding).
//   rows: channel-merged fused deconvolve/pad/fftshift + 512-pt row FFT.
//         Both channels ride in a float4 (re0,im0,re1,im1). Stage-0 fused
//         into staging (pair partner always zero) -> 8 radix-2 stages.
//   cols: 4-column tiles, float4 butterflies; stage-0 fused into load (zero
//         middle rows never touch LDS), stage loop unrolled w/ hoisted
//         twiddles (11 sincos). Output packed bf16x4 into the never-written
//         middle-row region of G32 (exact 2 MB/image fit).
//   gather: 8 lanes per (b,point); per row-tap ONE 8B load/lane yields both
//         channels. rsq/__expf/v_rcp weight path.
// Shift algebra: ifftshift(FFT(fftshift(p)))[(ind+256)%512] == FFT(fftshift(p))[ind&511].
// Output PLANAR: real plane (B,C,M) then imag plane.
// R4: no forced __launch_bounds__ minima (spill -> dead kernel).
// ---------------------------------------------------------------------------

#define NGRID 512
#define NSMALL 256
#define MW 4
#define BB 2
#define CC 2
#define MPTS 200000
#define PLANE (BB * CC * MPTS)   // imag-plane offset in floats
#define LPAD4 513                // LDS pitch in float4 (breaks pow2 banking)
#define IMG4 (NGRID * NGRID)     // float4 elems per b-image in G32
// G16 (uint2 units): image b's packed grid lives in G32's middle rows
#define G16OFF(b) ((size_t)(b) * 524288 + 131072)

// I0(z) asymptotic series, valid z > 8 (our z in [17.7, 18.9])
__device__ __forceinline__ float nfft29781_i0_large(float z) {
    float inv = __builtin_amdgcn_rcpf(z);
    float p = 1.0f + inv * (0.125f + inv * (0.0703125f
              + inv * (0.0732421875f + inv * 0.112152099609375f)));
    return __expf(z) * rsqrtf(2.0f * (float)M_PI * z) * p;
}

__device__ __forceinline__ int nfft29781_brev9(int v) {
    return (int)(__brev((unsigned)v) >> 23);
}

__device__ __forceinline__ unsigned nfft29781_bf16pack(float a, float b) {
    unsigned ua = __float_as_uint(a);
    ua += 0x7FFFu + ((ua >> 16) & 1u);           // RNE
    unsigned ub = __float_as_uint(b);
    ub += 0x7FFFu + ((ub >> 16) & 1u);
    return (ua >> 16) | (ub & 0xFFFF0000u);
}

// ---------------------------------------------------------------------------
// Rows (R10-proven): one block per (b, a1), a1 in [0,256); both channels.
// Staged col j2 = (tid<128)? tid : tid+256 (always outside [128,384)).
// Stage 0 fused: pair partner is always zero -> write (v, v) or (v, -v).
// ---------------------------------------------------------------------------
__global__ __launch_bounds__(256) void nfft29781_rows2(const float* __restrict__ fr,
                                                       const float* __restrict__ fi,
                                                       float4* __restrict__ G32) {
    __shared__ float4 s[NGRID];
    int tid = threadIdx.x;
    int b   = blockIdx.x >> 8;
    int a1  = blockIdx.x & 255;

    const float bcon  = 1.5f * (float)M_PI;
    const float scale = 2.0f * (float)M_PI / (float)NGRID;
    float k1 = (float)(a1 - 128) * scale;
    float p1 = nfft29781_i0_large((float)MW * sqrtf(bcon * bcon - k1 * k1));

    int a2 = tid ^ 128;
    float k2 = (float)(a2 - 128) * scale;
    float p2 = nfft29781_i0_large((float)MW * sqrtf(bcon * bcon - k2 * k2));
    float invp = __builtin_amdgcn_rcpf(p1 * p2);

    size_t s0 = ((size_t)(b * CC + 0) * NSMALL + a1) * NSMALL + a2;
    size_t s1 = ((size_t)(b * CC + 1) * NSMALL + a1) * NSMALL + a2;
    float4 v = make_float4(fr[s0] * invp, fi[s0] * invp,
                           fr[s1] * invp, fi[s1] * invp);

    // fused stage 0: nonzero staged col j2v pairs with an all-zero partner.
    int j2v = (tid < 128) ? tid : tid + 256;
    int pidx = nfft29781_brev9(j2v);
    int pe = pidx & ~1;
    s[pe]     = v;
    s[pe + 1] = (pidx & 1) ? make_float4(-v.x, -v.y, -v.z, -v.w) : v;
    __syncthreads();

    // stages 1..8
    #pragma unroll
    for (int st = 1; st < 9; ++st) {
        int half = 1 << st;
        int pos = tid & (half - 1);
        int i0 = ((tid >> st) << (st + 1)) + pos;
        int i1 = i0 + half;
        float sn, cs;
        if (st == 1) {                          // twiddle is 1 or -i: no sincos
            cs = pos ? 0.0f : 1.0f;
            sn = pos ? -1.0f : 0.0f;
        } else {
            float ang = -(float)M_PI * (float)pos / (float)half;
            __sincosf(ang, &sn, &cs);
        }
        float4 a = s[i0];
        float4 bq = s[i1];
        float4 tw;
        tw.x = bq.x * cs - bq.y * sn;  tw.y = bq.x * sn + bq.y * cs;
        tw.z = bq.z * cs - bq.w * sn;  tw.w = bq.z * sn + bq.w * cs;
        s[i0] = make_float4(a.x + tw.x, a.y + tw.y, a.z + tw.z, a.w + tw.w);
        s[i1] = make_float4(a.x - tw.x, a.y - tw.y, a.z - tw.z, a.w - tw.w);
        __syncthreads();
    }

    int j1 = (a1 < 128) ? a1 + 384 : a1 - 128;      // staged row (fftshift fold)
    float4* Gb = G32 + (size_t)b * IMG4 + (size_t)j1 * NGRID;
    Gb[tid]       = s[tid];
    Gb[tid + 256] = s[tid + 256];
}

// ---------------------------------------------------------------------------
// Cols (R10-proven): one block per (b, 4-col group); 256 blocks. Reads the
// 256 nonzero rows (fp32 float4); stage 0 fused into staging; 8 unrolled
// stages with hoisted/CSE'd twiddles; packs to bf16x4 into G32's middle rows.
// ---------------------------------------------------------------------------
__global__ __launch_bounds__(256) void nfft29781_cols2(float4* __restrict__ G32) {
    __shared__ float4 s[4 * LPAD4];                 // 32.8 KB
    int tid  = threadIdx.x;
    int b    = blockIdx.x >> 7;
    int col0 = (blockIdx.x & 127) << 2;
    const float4* Gb = G32 + (size_t)b * IMG4;

    // load 256 nonzero rows x 4 cols; fused stage 0: each bit-reversed
    // stage-0 pair (r, r+256) has exactly one nonzero member.
    #pragma unroll
    for (int it = 0; it < 4; ++it) {
        int e  = it * 256 + tid;                    // 0..1023
        int cp = e & 3;
        int q  = e >> 2;                            // 0..255
        int r  = (q < 128) ? q : q + 256;           // nonzero row
        float4 v = Gb[(size_t)r * NGRID + col0 + cp];
        int pidx = nfft29781_brev9(r);
        int pe = pidx & ~1;
        float4* scw = s + cp * LPAD4;
        scw[pe]     = v;
        scw[pe + 1] = (pidx & 1) ? make_float4(-v.x, -v.y, -v.z, -v.w) : v;
    }
    __syncthreads();

    // 4 column-FFTs in parallel: c owns a column, w does 4 butterflies/stage.
    // Stage loop fully unrolled: half compile-time, twiddles hoisted.
    int c = tid & 3;
    int w = tid >> 2;                               // 0..63
    float4* sc = s + c * LPAD4;
    #pragma unroll
    for (int st = 1; st < 9; ++st) {
        const int half = 1 << st;
        float csk[4], snk[4];
        if (st <= 6) {
            int pos = w & (half - 1);
            float sn, cs;
            if (st == 1) {                          // twiddle 1 or -i
                cs = pos ? 0.0f : 1.0f;
                sn = pos ? -1.0f : 0.0f;
            } else {
                float ang = -(float)M_PI * (float)pos / (float)half;
                __sincosf(ang, &sn, &cs);
            }
            csk[0] = csk[1] = csk[2] = csk[3] = cs;
            snk[0] = snk[1] = snk[2] = snk[3] = sn;
        } else if (st == 7) {
            #pragma unroll
            for (int k = 0; k < 2; ++k) {
                int pos = (w + (k << 6)) & 127;
                float ang = -(float)M_PI * (float)pos / 128.0f;
                __sincosf(ang, &snk[k], &csk[k]);
            }
            csk[2] = csk[0]; snk[2] = snk[0];
            csk[3] = csk[1]; snk[3] = snk[1];
        } else {
            #pragma unroll
            for (int k = 0; k < 4; ++k) {
                int pos = w + (k << 6);
                float ang = -(float)M_PI * (float)pos / 256.0f;
                __sincosf(ang, &snk[k], &csk[k]);
            }
        }
        #pragma unroll
        for (int k = 0; k < 4; ++k) {
            int bf  = w + (k << 6);                 // 0..255
            int pos = bf & (half - 1);
            int i0  = ((bf >> st) << (st + 1)) + pos;
            int i1  = i0 + half;
            float cs = csk[k], sn = snk[k];
            float4 a = sc[i0];
            float4 bb = sc[i1];
            float4 tw;
            tw.x = bb.x * cs - bb.y * sn;  tw.y = bb.x * sn + bb.y * cs;
            tw.z = bb.z * cs - bb.w * sn;  tw.w = bb.z * sn + bb.w * cs;
            sc[i0] = make_float4(a.x + tw.x, a.y + tw.y, a.z + tw.z, a.w + tw.w);
            sc[i1] = make_float4(a.x - tw.x, a.y - tw.y, a.z - tw.z, a.w - tw.w);
        }
        __syncthreads();
    }

    // pack + write all 512 rows x 4 cols into the middle-row region (uint2)
    uint2* G16 = (uint2*)G32 + G16OFF(b);
    #pragma unroll
    for (int it = 0; it < 8; ++it) {
        int e  = it * 256 + tid;                    // 0..2047
        int cp = e & 3;
        int r  = e >> 2;                            // 0..511
        float4 v = s[cp * LPAD4 + r];
        uint2 pk;
        pk.x = nfft29781_bf16pack(v.x, v.y);        // ch0 re|im
        pk.y = nfft29781_bf16pack(v.z, v.w);        // ch1 re|im
        G16[(size_t)r * NGRID + col0 + cp] = pk;
    }
}

// ---------------------------------------------------------------------------
// Gather: 8 lanes per (b,point); lane j owns column-tap j. R15 schedule:
// all 8 scattered loads batched upfront (registers), all 8 w0 broadcasts
// batched after, float2 accumulation (v_pk_fma candidate). Same memory
// pattern / wave count / arithmetic order as the proven R10 kernel.
// ---------------------------------------------------------------------------
__global__ __launch_bounds__(256) void nfft29781_gather_bf16(const float* __restrict__ x,
                                                             const uint2* __restrict__ G16base,
                                                             float* __restrict__ out,
                                                             int out_elems) {
    int t  = blockIdx.x * blockDim.x + threadIdx.x;
    int j  = t & 7;                  // my column tap
    int pp = t >> 3;                 // (b, point) id — shared by 8 group lanes
    if (pp >= BB * MPTS) return;
    int b  = (pp >= MPTS) ? 1 : 0;
    int pt = pp - b * MPTS;

    float u0 = x[(size_t)pp * 2 + 0] * (float)NGRID;   // broadcast within group
    float u1 = x[(size_t)pp * 2 + 1] * (float)NGRID;

    float c0 = ceilf(u0), c1 = ceilf(u1);
    int base0 = (int)c0 - MW;
    int base1 = (int)c1 - MW;
    float d0 = c0 - u0, d1 = c1 - u1;

    const float bw = 1.5f * (float)M_PI;
    const float invpi = 1.0f / (float)M_PI;
    float w0m, w1m;   // my dim-0 / dim-1 tap-j weights
    {
        float nk = (float)(MW - j) - d0;
        float tt = (float)(MW * MW) - nk * nk;
        w0m = 0.0f;
        if (tt > 0.0f) {
            float ra = __builtin_amdgcn_rsqf(tt);    // 1/a
            float a  = tt * ra;                      // a = sqrt(tt)
            float e  = __expf(bw * a);
            w0m = (e - __builtin_amdgcn_rcpf(e)) * (0.5f * invpi) * ra;
        }
        nk = (float)(MW - j) - d1;
        tt = (float)(MW * MW) - nk * nk;
        w1m = 0.0f;
        if (tt > 0.0f) {
            float ra = __builtin_amdgcn_rsqf(tt);
            float a  = tt * ra;
            float e  = __expf(bw * a);
            w1m = (e - __builtin_amdgcn_rcpf(e)) * (0.5f * invpi) * ra;
        }
    }

    const uint2* Gi = G16base + G16OFF(b);
    int cix = (base1 + j) & (NGRID - 1);
    int lanebase = (threadIdx.x & 63) & ~7;

    // batch 1: issue all 8 independent scattered loads (one vmcnt group)
    uint2 g[8];
    #pragma unroll
    for (int i = 0; i < 8; ++i) {
        g[i] = Gi[(size_t)(((base0 + i) & (NGRID - 1)) << 9) + cix];
    }
    // batch 2: all 8 row-weight broadcasts (one lgkm group)
    float w0[8];
    #pragma unroll
    for (int i = 0; i < 8; ++i) {
        w0[i] = __shfl(w0m, lanebase + i, 64);
    }

    // weighted accumulation as float2 pairs (re,im) — pk-FMA candidate
    float2 acc0 = make_float2(0.0f, 0.0f);
    float2 acc1 = make_float2(0.0f, 0.0f);
    #pragma unroll
    for (int i = 0; i < 8; ++i) {
        float2 v0 = make_float2(__uint_as_float(g[i].x << 16),
                                __uint_as_float(g[i].x & 0xFFFF0000u));
        float2 v1 = make_float2(__uint_as_float(g[i].y << 16),
                                __uint_as_float(g[i].y & 0xFFFF0000u));
        acc0.x += w0[i] * v0.x;  acc0.y += w0[i] * v0.y;
        acc1.x += w0[i] * v1.x;  acc1.y += w0[i] * v1.y;
    }
    float a0x = acc0.x * w1m, a0y = acc0.y * w1m;
    float a1x = acc1.x * w1m, a1y = acc1.y * w1m;

    #pragma unroll
    for (int msk = 1; msk < 8; msk <<= 1) {          // sum the 8 column taps
        a0x += __shfl_xor(a0x, msk, 64);
        a0y += __shfl_xor(a0y, msk, 64);
        a1x += __shfl_xor(a1x, msk, 64);
        a1y += __shfl_xor(a1y, msk, 64);
    }

    if (j == 0) {
        size_t o0 = (size_t)(b * CC) * MPTS + pt;    // channel 0
        size_t o1 = o0 + MPTS;                       // channel 1
        if (o0 < (size_t)out_elems)         out[o0]         = a0x;
        if (PLANE + o0 < (size_t)out_elems) out[PLANE + o0] = a0y;
        if (o1 < (size_t)out_elems)         out[o1]         = a1x;
        if (PLANE + o1 < (size_t)out_elems) out[PLANE + o1] = a1y;
    }
}

extern "C" void kernel_launch(void* const* d_in, const int* in_sizes, int n_in,
                              void* d_out, int out_size, void* d_ws, size_t ws_size,
                              hipStream_t stream) {
    (void)in_sizes; (void)n_in;
    const float* x  = (const float*)d_in[0];
    const float* fr = (const float*)d_in[1];
    const float* fi = (const float*)d_in[2];
    float*  out = (float*)d_out;
    float4* G32 = (float4*)d_ws;        // BB * 512*512 float4 = 8 MB

    const size_t fullBytes = (size_t)BB * IMG4 * sizeof(float4);
    if (ws_size < fullBytes) return;    // diagnostic no-op (ws proven >= 8 MB)

    nfft29781_rows2<<<BB * NSMALL, 256, 0, stream>>>(fr, fi, G32);
    nfft29781_cols2<<<BB * (NGRID / 4), 256, 0, stream>>>(G32);
    int gthreads = BB * MPTS * 8;       // 8 lanes per (b,point), both channels
    nfft29781_gather_bf16<<<(gthreads + 255) / 256, 256, 0, stream>>>(
        x, (const uint2*)d_ws, out, out_size);
}

// Round 7
// 95.142 us; speedup vs baseline: 1.4939x; 1.0076x over previous
//
#include <hip/hip_runtime.h>
#include <math.h>

// ---------------------------------------------------------------------------
// NFFT forward (type-2): f_hat (B,C,256,256 complex) -> samples at M points.
// R16 == R10 exact restore (best measured: 94.95us). Session findings:
//   - R11 (radix-4 FFT + 4-lane gather): regressed — gather is latency-bound,
//     halving waves halves latency hiding.
//   - R12 (fused rows+cols via spin barrier): catastrophic — ANY cross-XCD
//     rendezvous costs ~45us on 8 XCDs (matches R8 cooperative-launch).
//   - R14 (2-row/block rows, 2-col cols): -1.4us regression.
//   - R15 (batched-load gather schedule): neutral — gather is not
//     issue-order-limited; it sits at the L2 random-access latency bound.
// Structure: 3 dispatches.
//   rows: channel-merged fused deconvolve/pad/fftshift + 512-pt row FFT.
//         Both channels of one b-image ride in a float4 (re0,im0,re1,im1),
//         sharing twiddles. Stage-0 fused into staging (each bit-reversed
//         stage-0 pair has exactly one nonzero input -> write (v, +/-v),
//         no zero fill, 8 radix-2 stages).
//   cols: 4-column tiles, float4 butterflies; stage-0 fused into the load
//         (zero middle rows never touch LDS), stage loop fully unrolled with
//         hoisted twiddles (11 sincos/thread). Output packed to bf16x4 into
//         the never-written middle-row region of G32 (exact 2 MB/image fit).
//   gather: 8 lanes per (b,point); per row-tap ONE 8B load/lane yields both
//         channels (bf16x4). fp32 accumulation; single bf16 rounding layer.
//         rsq gives a and 1/a together; __expf + v_rcp replace libm.
// Shift algebra: ifftshift(FFT(fftshift(p)))[(ind+256)%512] == FFT(fftshift(p))[ind&511].
// Output PLANAR: real plane (B,C,M) then imag plane.
// R4: no forced __launch_bounds__ minima (spill -> dead kernel).
// ---------------------------------------------------------------------------

#define NGRID 512
#define NSMALL 256
#define MW 4
#define BB 2
#define CC 2
#define MPTS 200000
#define PLANE (BB * CC * MPTS)   // imag-plane offset in floats
#define LPAD4 513                // LDS pitch in float4 (breaks pow2 banking)
#define IMG4 (NGRID * NGRID)     // float4 elems per b-image in G32
// G16 (uint2 units): image b's packed grid lives in G32's middle rows
#define G16OFF(b) ((size_t)(b) * 524288 + 131072)

// I0(z) asymptotic series, valid z > 8 (our z in [17.7, 18.9])
__device__ __forceinline__ float nfft29781_i0_large(float z) {
    float inv = __builtin_amdgcn_rcpf(z);
    float p = 1.0f + inv * (0.125f + inv * (0.0703125f
              + inv * (0.0732421875f + inv * 0.112152099609375f)));
    return __expf(z) * rsqrtf(2.0f * (float)M_PI * z) * p;
}

__device__ __forceinline__ int nfft29781_brev9(int v) {
    return (int)(__brev((unsigned)v) >> 23);
}

__device__ __forceinline__ unsigned nfft29781_bf16pack(float a, float b) {
    unsigned ua = __float_as_uint(a);
    ua += 0x7FFFu + ((ua >> 16) & 1u);           // RNE
    unsigned ub = __float_as_uint(b);
    ub += 0x7FFFu + ((ub >> 16) & 1u);
    return (ua >> 16) | (ub & 0xFFFF0000u);
}

// ---------------------------------------------------------------------------
// Rows: one block per (b, a1), a1 in [0,256) = f_hat row; both channels.
// Staged col j2 = (tid<128)? tid : tid+256 (always outside [128,384)).
// Stage 0 fused: pair partner is always zero -> write (v, v) or (v, -v).
// ---------------------------------------------------------------------------
__global__ __launch_bounds__(256) void nfft29781_rows2(const float* __restrict__ fr,
                                                       const float* __restrict__ fi,
                                                       float4* __restrict__ G32) {
    __shared__ float4 s[NGRID];
    int tid = threadIdx.x;
    int b   = blockIdx.x >> 8;
    int a1  = blockIdx.x & 255;

    const float bcon  = 1.5f * (float)M_PI;
    const float scale = 2.0f * (float)M_PI / (float)NGRID;
    float k1 = (float)(a1 - 128) * scale;
    float p1 = nfft29781_i0_large((float)MW * sqrtf(bcon * bcon - k1 * k1));

    int a2 = tid ^ 128;
    float k2 = (float)(a2 - 128) * scale;
    float p2 = nfft29781_i0_large((float)MW * sqrtf(bcon * bcon - k2 * k2));
    float invp = __builtin_amdgcn_rcpf(p1 * p2);

    size_t s0 = ((size_t)(b * CC + 0) * NSMALL + a1) * NSMALL + a2;
    size_t s1 = ((size_t)(b * CC + 1) * NSMALL + a1) * NSMALL + a2;
    float4 v = make_float4(fr[s0] * invp, fi[s0] * invp,
                           fr[s1] * invp, fi[s1] * invp);

    // fused stage 0: nonzero staged col j2v pairs with an all-zero partner.
    // p even (j2v<256): s[p]=v, s[p+1]=v.  p odd (j2v>=256): s[p-1]=v, s[p]=-v.
    int j2v = (tid < 128) ? tid : tid + 256;
    int pidx = nfft29781_brev9(j2v);
    int pe = pidx & ~1;
    s[pe]     = v;
    s[pe + 1] = (pidx & 1) ? make_float4(-v.x, -v.y, -v.z, -v.w) : v;
    __syncthreads();

    // stages 1..8
    #pragma unroll
    for (int st = 1; st < 9; ++st) {
        int half = 1 << st;
        int pos = tid & (half - 1);
        int i0 = ((tid >> st) << (st + 1)) + pos;
        int i1 = i0 + half;
        float sn, cs;
        if (st == 1) {                          // twiddle is 1 or -i: no sincos
            cs = pos ? 0.0f : 1.0f;
            sn = pos ? -1.0f : 0.0f;
        } else {
            float ang = -(float)M_PI * (float)pos / (float)half;
            __sincosf(ang, &sn, &cs);
        }
        float4 a = s[i0];
        float4 bq = s[i1];
        float4 tw;
        tw.x = bq.x * cs - bq.y * sn;  tw.y = bq.x * sn + bq.y * cs;
        tw.z = bq.z * cs - bq.w * sn;  tw.w = bq.z * sn + bq.w * cs;
        s[i0] = make_float4(a.x + tw.x, a.y + tw.y, a.z + tw.z, a.w + tw.w);
        s[i1] = make_float4(a.x - tw.x, a.y - tw.y, a.z - tw.z, a.w - tw.w);
        __syncthreads();
    }

    int j1 = (a1 < 128) ? a1 + 384 : a1 - 128;      // staged row (fftshift fold)
    float4* Gb = G32 + (size_t)b * IMG4 + (size_t)j1 * NGRID;
    Gb[tid]       = s[tid];
    Gb[tid + 256] = s[tid + 256];
}

// ---------------------------------------------------------------------------
// Cols: one block per (b, 4-col group); 256 blocks. Reads the 256 nonzero
// rows (fp32 float4); stage 0 fused into staging (middle-row zeros never
// touch LDS); 8 unrolled stages with hoisted/CSE'd twiddles; packs result to
// bf16x4 into G32's middle-row region (disjoint from reads).
// ---------------------------------------------------------------------------
__global__ __launch_bounds__(256) void nfft29781_cols2(float4* __restrict__ G32) {
    __shared__ float4 s[4 * LPAD4];                 // 32.8 KB
    int tid  = threadIdx.x;
    int b    = blockIdx.x >> 7;
    int col0 = (blockIdx.x & 127) << 2;
    const float4* Gb = G32 + (size_t)b * IMG4;

    // load 256 nonzero rows x 4 cols; fused stage 0: each bit-reversed
    // stage-0 pair (r, r+256) has exactly one nonzero member.
    #pragma unroll
    for (int it = 0; it < 4; ++it) {
        int e  = it * 256 + tid;                    // 0..1023
        int cp = e & 3;
        int q  = e >> 2;                            // 0..255
        int r  = (q < 128) ? q : q + 256;           // nonzero row
        float4 v = Gb[(size_t)r * NGRID + col0 + cp];
        int pidx = nfft29781_brev9(r);
        int pe = pidx & ~1;
        float4* scw = s + cp * LPAD4;
        scw[pe]     = v;
        scw[pe + 1] = (pidx & 1) ? make_float4(-v.x, -v.y, -v.z, -v.w) : v;
    }
    __syncthreads();

    // 4 column-FFTs in parallel: c owns a column, w does 4 butterflies/stage.
    // Stage loop fully unrolled: half compile-time, twiddles hoisted.
    // half<=64: pos identical for all k -> 1 sincos. half==128: 2. 256: 4.
    int c = tid & 3;
    int w = tid >> 2;                               // 0..63
    float4* sc = s + c * LPAD4;
    #pragma unroll
    for (int st = 1; st < 9; ++st) {
        const int half = 1 << st;
        float csk[4], snk[4];
        if (st <= 6) {
            int pos = w & (half - 1);
            float sn, cs;
            if (st == 1) {                          // twiddle 1 or -i
                cs = pos ? 0.0f : 1.0f;
                sn = pos ? -1.0f : 0.0f;
            } else {
                float ang = -(float)M_PI * (float)pos / (float)half;
                __sincosf(ang, &sn, &cs);
            }
            csk[0] = csk[1] = csk[2] = csk[3] = cs;
            snk[0] = snk[1] = snk[2] = snk[3] = sn;
        } else if (st == 7) {
            #pragma unroll
            for (int k = 0; k < 2; ++k) {
                int pos = (w + (k << 6)) & 127;
                float ang = -(float)M_PI * (float)pos / 128.0f;
                __sincosf(ang, &snk[k], &csk[k]);
            }
            csk[2] = csk[0]; snk[2] = snk[0];
            csk[3] = csk[1]; snk[3] = snk[1];
        } else {
            #pragma unroll
            for (int k = 0; k < 4; ++k) {
                int pos = w + (k << 6);
                float ang = -(float)M_PI * (float)pos / 256.0f;
                __sincosf(ang, &snk[k], &csk[k]);
            }
        }
        #pragma unroll
        for (int k = 0; k < 4; ++k) {
            int bf  = w + (k << 6);                 // 0..255
            int pos = bf & (half - 1);
            int i0  = ((bf >> st) << (st + 1)) + pos;
            int i1  = i0 + half;
            float cs = csk[k], sn = snk[k];
            float4 a = sc[i0];
            float4 bb = sc[i1];
            float4 tw;
            tw.x = bb.x * cs - bb.y * sn;  tw.y = bb.x * sn + bb.y * cs;
            tw.z = bb.z * cs - bb.w * sn;  tw.w = bb.z * sn + bb.w * cs;
            sc[i0] = make_float4(a.x + tw.x, a.y + tw.y, a.z + tw.z, a.w + tw.w);
            sc[i1] = make_float4(a.x - tw.x, a.y - tw.y, a.z - tw.z, a.w - tw.w);
        }
        __syncthreads();
    }

    // pack + write all 512 rows x 4 cols into the middle-row region (uint2)
    uint2* G16 = (uint2*)G32 + G16OFF(b);
    #pragma unroll
    for (int it = 0; it < 8; ++it) {
        int e  = it * 256 + tid;                    // 0..2047
        int cp = e & 3;
        int r  = e >> 2;                            // 0..511
        float4 v = s[cp * LPAD4 + r];
        uint2 pk;
        pk.x = nfft29781_bf16pack(v.x, v.y);        // ch0 re|im
        pk.y = nfft29781_bf16pack(v.z, v.w);        // ch1 re|im
        G16[(size_t)r * NGRID + col0 + cp] = pk;
    }
}

// ---------------------------------------------------------------------------
// Gather: 8 lanes per (b,point); lane j owns column-tap j. Per row-tap ONE
// 8B load/lane -> both channels (bf16x4). Weights computed once per group,
// w0[i] broadcast via __shfl; 3-stage __shfl_xor sums; lane 0 writes planar.
// Weight sequence bit-matches reference ceil(x*n)-m. rsq gives a and 1/a
// together; __expf + v_rcp replace libm expf + 2 precise divides.
// ---------------------------------------------------------------------------
__global__ __launch_bounds__(256) void nfft29781_gather_bf16(const float* __restrict__ x,
                                                             const uint2* __restrict__ G16base,
                                                             float* __restrict__ out,
                                                             int out_elems) {
    int t  = blockIdx.x * blockDim.x + threadIdx.x;
    int j  = t & 7;                  // my column tap
    int pp = t >> 3;                 // (b, point) id — shared by 8 group lanes
    if (pp >= BB * MPTS) return;
    int b  = (pp >= MPTS) ? 1 : 0;
    int pt = pp - b * MPTS;

    float u0 = x[(size_t)pp * 2 + 0] * (float)NGRID;   // broadcast within group
    float u1 = x[(size_t)pp * 2 + 1] * (float)NGRID;

    float c0 = ceilf(u0), c1 = ceilf(u1);
    int base0 = (int)c0 - MW;
    int base1 = (int)c1 - MW;
    float d0 = c0 - u0, d1 = c1 - u1;

    const float bw = 1.5f * (float)M_PI;
    const float invpi = 1.0f / (float)M_PI;
    float w0m, w1m;   // my dim-0 / dim-1 tap-j weights
    {
        float nk = (float)(MW - j) - d0;
        float tt = (float)(MW * MW) - nk * nk;
        w0m = 0.0f;
        if (tt > 0.0f) {
            float ra = __builtin_amdgcn_rsqf(tt);    // 1/a
            float a  = tt * ra;                      // a = sqrt(tt)
            float e  = __expf(bw * a);
            w0m = (e - __builtin_amdgcn_rcpf(e)) * (0.5f * invpi) * ra;
        }
        nk = (float)(MW - j) - d1;
        tt = (float)(MW * MW) - nk * nk;
        w1m = 0.0f;
        if (tt > 0.0f) {
            float ra = __builtin_amdgcn_rsqf(tt);
            float a  = tt * ra;
            float e  = __expf(bw * a);
            w1m = (e - __builtin_amdgcn_rcpf(e)) * (0.5f * invpi) * ra;
        }
    }

    const uint2* Gi = G16base + G16OFF(b);
    int cix = (base1 + j) & (NGRID - 1);
    int lanebase = (threadIdx.x & 63) & ~7;

    float a0x = 0.0f, a0y = 0.0f, a1x = 0.0f, a1y = 0.0f;
    #pragma unroll
    for (int i = 0; i < 8; ++i) {
        float w0i = __shfl(w0m, lanebase + i, 64);   // row-i weight
        uint2 g = Gi[(size_t)(((base0 + i) & (NGRID - 1)) << 9) + cix];
        float g0x = __uint_as_float(g.x << 16);
        float g0y = __uint_as_float(g.x & 0xFFFF0000u);
        float g1x = __uint_as_float(g.y << 16);
        float g1y = __uint_as_float(g.y & 0xFFFF0000u);
        a0x += w0i * g0x;  a0y += w0i * g0y;
        a1x += w0i * g1x;  a1y += w0i * g1y;
    }
    a0x *= w1m;  a0y *= w1m;  a1x *= w1m;  a1y *= w1m;

    #pragma unroll
    for (int msk = 1; msk < 8; msk <<= 1) {          // sum the 8 column taps
        a0x += __shfl_xor(a0x, msk, 64);
        a0y += __shfl_xor(a0y, msk, 64);
        a1x += __shfl_xor(a1x, msk, 64);
        a1y += __shfl_xor(a1y, msk, 64);
    }

    if (j == 0) {
        size_t o0 = (size_t)(b * CC) * MPTS + pt;    // channel 0
        size_t o1 = o0 + MPTS;                       // channel 1
        if (o0 < (size_t)out_elems)         out[o0]         = a0x;
        if (PLANE + o0 < (size_t)out_elems) out[PLANE + o0] = a0y;
        if (o1 < (size_t)out_elems)         out[o1]         = a1x;
        if (PLANE + o1 < (size_t)out_elems) out[PLANE + o1] = a1y;
    }
}

extern "C" void kernel_launch(void* const* d_in, const int* in_sizes, int n_in,
                              void* d_out, int out_size, void* d_ws, size_t ws_size,
                              hipStream_t stream) {
    (void)in_sizes; (void)n_in;
    const float* x  = (const float*)d_in[0];
    const float* fr = (const float*)d_in[1];
    const float* fi = (const float*)d_in[2];
    float*  out = (float*)d_out;
    float4* G32 = (float4*)d_ws;        // BB * 512*512 float4 = 8 MB

    const size_t fullBytes = (size_t)BB * IMG4 * sizeof(float4);
    if (ws_size < fullBytes) return;    // diagnostic no-op (ws proven >= 8 MB)

    nfft29781_rows2<<<BB * NSMALL, 256, 0, stream>>>(fr, fi, G32);
    nfft29781_cols2<<<BB * (NGRID / 4), 256, 0, stream>>>(G32);
    int gthreads = BB * MPTS * 8;       // 8 lanes per (b,point), both channels
    nfft29781_gather_bf16<<<(gthreads + 255) / 256, 256, 0, stream>>>(
        x, (const uint2*)d_ws, out, out_size);
}